// Round 3
// baseline (298.851 us; speedup 1.0000x reference)
//
#include <hip/hip_runtime.h>
#include <cstdint>

#define NROWS 16384
#define FDIM 64
#define HDIM 128
#define ODIM 512
#define KDIM 8192   // FDIM * HDIM
#define NSTEPS 128  // KDIM / BK

#define BM 64
#define BN 512
#define BK 64

typedef short bf16x8 __attribute__((ext_vector_type(8)));
typedef float f32x4 __attribute__((ext_vector_type(4)));
typedef uint32_t u32x4 __attribute__((ext_vector_type(4)));

__device__ __forceinline__ uint16_t rne_bf16(float f) {
  uint32_t u = __builtin_bit_cast(uint32_t, f);
  u += 0x7fffu + ((u >> 16) & 1u);
  return (uint16_t)(u >> 16);
}

// ---- pre-kernel 1: W2 [K=8192][O=512] f32 -> W2T [O][K] bf16 (LDS tile transpose) ----
__global__ void prep_w2t(const float* __restrict__ W2, uint16_t* __restrict__ W2T) {
  __shared__ float tile[64][65];
  const int k0 = blockIdx.x * 64;
  const int o0 = blockIdx.y * 64;
  const int tx = threadIdx.x;  // 0..63
  const int ty = threadIdx.y;  // 0..7
#pragma unroll
  for (int j = 0; j < 8; ++j)
    tile[ty + 8 * j][tx] = W2[(size_t)(k0 + ty + 8 * j) * ODIM + o0 + tx];
  __syncthreads();
#pragma unroll
  for (int j = 0; j < 8; ++j)
    W2T[(size_t)(o0 + ty + 8 * j) * KDIM + k0 + tx] = rne_bf16(tile[tx][ty + 8 * j]);
}

// ---- pre-kernel 2: bf16 copies of W1/b1, and b2sum[o] = sum_f b2[f][o] ----
__global__ void prep_small(const float* __restrict__ W1, const float* __restrict__ b1,
                           const float* __restrict__ b2, uint16_t* __restrict__ w1bf,
                           uint16_t* __restrict__ b1bf, float* __restrict__ b2sum) {
  const int t = blockIdx.x * 256 + threadIdx.x;  // grid 32*256 = 8192 = F*H
  w1bf[t] = rne_bf16(W1[t]);
  b1bf[t] = rne_bf16(b1[t]);
  if (t < ODIM) {
    float s = 0.f;
#pragma unroll
    for (int f = 0; f < FDIM; ++f) s += b2[(size_t)f * ODIM + t];
    b2sum[t] = s;
  }
}

// ---- main fused kernel ----
// BM=64 x BN=512 (full O per block -> elu computed exactly once per element).
// 512 threads = 8 waves; wave w covers cols [w*64, w*64+64) x all 64 rows.
// Double-buffered As/Bs (144KB LDS), ONE barrier per k-step; B async-loads for
// step s+1 are issued at the top of step s so the barrier's vmcnt drain is
// hidden under this step's elu+MFMA. Waves 0-3 do (gen s+1, mfma s); waves 4-7
// do (mfma s, gen s+1) -> each SIMD (hosting wave i and i+4) always has one
// wave in the VALU phase and one in the MFMA phase.
__global__ __launch_bounds__(512, 2) void mlp_gemm(
    const float* __restrict__ x, const uint16_t* __restrict__ w1bf,
    const uint16_t* __restrict__ b1bf, const uint16_t* __restrict__ W2T,
    const float* __restrict__ b2sum, float* __restrict__ out) {
  __shared__ __align__(16) uint16_t As[2][BM * BK];  // 2 x 8 KB
  __shared__ __align__(16) uint16_t Bs[2][BN * BK];  // 2 x 64 KB

  const int tid = threadIdx.x;
  const int m0 = blockIdx.x * BM;

  const int wid = tid >> 6;
  const int lane = tid & 63;
  const int wn = wid * 64;   // wave's O-column slice
  const int q = lane >> 4;   // quad
  const int r = lane & 15;

  // A-gen roles: one row per lane
  const int ar = tid >> 3;  // 0..63
  const int ac = tid & 7;   // col group (8 bf16)
  // B-staging roles (global_load_lds: LDS = wave-uniform base + lane*16;
  // swizzle the GLOBAL col-group so fragment reads stay conflict-free)
  const int brow = lane >> 3;           // 0..7 within an 8-row chunk
  const int bcg = (lane & 7) ^ brow;    // swizzled col group

  f32x4 acc[4][4];
#pragma unroll
  for (int i = 0; i < 4; ++i)
#pragma unroll
    for (int j = 0; j < 4; ++j) acc[i][j] = {0.f, 0.f, 0.f, 0.f};

  // ---- helpers as lambdas (inlined) ----
  auto stageB = [&](int step, int buf) {
#pragma unroll
    for (int j = 0; j < 8; ++j) {
      const int chunk = wid * 8 + j;  // 0..63, 8 rows each
      const uint16_t* gp =
          W2T + (size_t)(chunk * 8 + brow) * KDIM + step * BK + bcg * 8;
      uint16_t* lp = &Bs[buf][chunk * 512];  // wave-uniform base
      __builtin_amdgcn_global_load_lds(
          (const __attribute__((address_space(1))) uint32_t*)gp,
          (__attribute__((address_space(3))) uint32_t*)lp, 16, 0, 0);
    }
  };

  auto genA = [&](int step, int buf) {
    const int f = step >> 1;
    const int half = step & 1;
    const float xv = x[(size_t)(m0 + ar) * FDIM + f];
    const int hoff = half * 64 + ac * 8;
    u32x4 w1d = *(const u32x4*)(w1bf + f * HDIM + hoff);
    u32x4 b1d = *(const u32x4*)(b1bf + f * HDIM + hoff);
    u32x4 ov;
#pragma unroll
    for (int p = 0; p < 4; ++p) {
      float wlo = __builtin_bit_cast(float, w1d[p] << 16);
      float whi = __builtin_bit_cast(float, w1d[p] & 0xffff0000u);
      float blo = __builtin_bit_cast(float, b1d[p] << 16);
      float bhi = __builtin_bit_cast(float, b1d[p] & 0xffff0000u);
      float plo = fmaf(xv, wlo, blo);
      float phi = fmaf(xv, whi, bhi);
      float elo = plo > 0.f ? plo : __expf(plo) - 1.f;
      float ehi = phi > 0.f ? phi : __expf(phi) - 1.f;
      ov[p] = __builtin_amdgcn_perm(__builtin_bit_cast(uint32_t, ehi),
                                    __builtin_bit_cast(uint32_t, elo),
                                    0x07060302u);
    }
    *(u32x4*)&As[buf][ar * BK + ((ac ^ (ar & 7)) * 8)] = ov;
  };

  auto domfma = [&](int buf) {
#pragma unroll
    for (int kc = 0; kc < 2; ++kc) {
      bf16x8 af[4], bfr[4];
      const int cg = kc * 4 + q;
#pragma unroll
      for (int mt = 0; mt < 4; ++mt) {
        const int row = mt * 16 + r;
        af[mt] = *(const bf16x8*)&As[buf][row * BK + ((cg ^ (row & 7)) * 8)];
      }
#pragma unroll
      for (int nt = 0; nt < 4; ++nt) {
        const int row = wn + nt * 16 + r;
        bfr[nt] = *(const bf16x8*)&Bs[buf][row * BK + ((cg ^ (row & 7)) * 8)];
      }
#pragma unroll
      for (int mt = 0; mt < 4; ++mt)
#pragma unroll
        for (int nt = 0; nt < 4; ++nt)
          acc[mt][nt] = __builtin_amdgcn_mfma_f32_16x16x32_bf16(
              af[mt], bfr[nt], acc[mt][nt], 0, 0, 0);
    }
  };

  // ---- prologue: stage step 0 into buffer 0 ----
  stageB(0, 0);
  genA(0, 0);

  // ---- main loop: one barrier per k-step ----
  for (int s = 0; s < NSTEPS; ++s) {
    const int cur = s & 1;
    const int nxt = cur ^ 1;
    __syncthreads();  // step-s B loads drained (vmcnt), A writes visible,
                      // nxt buffers free (consumed in step s-1)
    if (wid < 4) {
      if (s + 1 < NSTEPS) {
        stageB(s + 1, nxt);  // async loads fly during elu + mfma below
        genA(s + 1, nxt);
      }
      domfma(cur);
    } else {
      if (s + 1 < NSTEPS) stageB(s + 1, nxt);
      domfma(cur);
      if (s + 1 < NSTEPS) genA(s + 1, nxt);
    }
  }

  // ---- epilogue: + sum_f b2, * 1/sqrt(F) ----
  float bsv[4];
#pragma unroll
  for (int nt = 0; nt < 4; ++nt) bsv[nt] = b2sum[wn + nt * 16 + r];
#pragma unroll
  for (int mt = 0; mt < 4; ++mt)
#pragma unroll
    for (int nt = 0; nt < 4; ++nt)
#pragma unroll
      for (int v = 0; v < 4; ++v) {
        const int row = m0 + mt * 16 + q * 4 + v;  // C/D: row=(lane>>4)*4+reg
        const int col = wn + nt * 16 + r;          //      col=lane&15
        out[(size_t)row * ODIM + col] = (acc[mt][nt][v] + bsv[nt]) * 0.125f;
      }
}

extern "C" void kernel_launch(void* const* d_in, const int* in_sizes, int n_in,
                              void* d_out, int out_size, void* d_ws, size_t ws_size,
                              hipStream_t stream) {
  const float* x  = (const float*)d_in[0];
  const float* W1 = (const float*)d_in[1];
  const float* b1 = (const float*)d_in[2];
  const float* W2 = (const float*)d_in[3];
  const float* b2 = (const float*)d_in[4];
  float* out = (float*)d_out;

  char* ws = (char*)d_ws;
  float*    b2sum = (float*)ws;                       // 2KB
  uint16_t* w1bf  = (uint16_t*)(ws + 4096);           // 16KB
  uint16_t* b1bf  = (uint16_t*)(ws + 4096 + 16384);   // 16KB
  uint16_t* W2T   = (uint16_t*)(ws + 65536);          // 8MB [O][K] bf16

  prep_w2t<<<dim3(KDIM / 64, ODIM / 64), dim3(64, 8), 0, stream>>>(W2, W2T);
  prep_small<<<32, 256, 0, stream>>>(W1, b1, b2, w1bf, b1bf, b2sum);
  mlp_gemm<<<NROWS / BM, 512, 0, stream>>>(x, w1bf, b1bf, W2T, b2sum, out);
}

// Round 4
// 292.087 us; speedup vs baseline: 1.0232x; 1.0232x over previous
//
#include <hip/hip_runtime.h>
#include <cstdint>

#define NROWS 16384
#define FDIM 64
#define HDIM 128
#define ODIM 512
#define KDIM 8192   // FDIM * HDIM
#define NSTEPS 128  // KDIM / BK

#define BM 128
#define BN 256
#define BK 64

typedef short bf16x8 __attribute__((ext_vector_type(8)));
typedef float f32x4 __attribute__((ext_vector_type(4)));
typedef uint32_t u32x4 __attribute__((ext_vector_type(4)));

__device__ __forceinline__ uint16_t rne_bf16(float f) {
  uint32_t u = __builtin_bit_cast(uint32_t, f);
  u += 0x7fffu + ((u >> 16) & 1u);
  return (uint16_t)(u >> 16);
}

// ---- pre-kernel 1: W2 [K][O] f32 -> W2F fragment-linear bf16 ----
// Entry e (16B, one lane's 8 k-elems of one B fragment):
//   lane=e&63, nt=(e>>6)&3, wc=(e>>8)&3, kc=(e>>10)&1, step=(e>>11)&127, oh=e>>18
//   col = oh*256 + wc*64 + nt*16 + (lane&15)
//   k0  = step*64 + kc*32 + (lane>>4)*8
// Main kernel: wave (oh,wc) loads frag (step,kc,nt) as ONE contiguous 1KB block.
__global__ void prep_w2f(const float* __restrict__ W2, uint16_t* __restrict__ W2F) {
  const int e = blockIdx.x * 256 + threadIdx.x;  // 2048*256 = 524288 entries
  const int lane = e & 63;
  const int nt = (e >> 6) & 3;
  const int wc = (e >> 8) & 3;
  const int kc = (e >> 10) & 1;
  const int step = (e >> 11) & 127;
  const int oh = (e >> 18) & 1;
  const int col = oh * 256 + wc * 64 + nt * 16 + (lane & 15);
  const int k0 = step * 64 + kc * 32 + (lane >> 4) * 8;
  uint16_t v[8];
#pragma unroll
  for (int j = 0; j < 8; ++j) v[j] = rne_bf16(W2[(size_t)(k0 + j) * ODIM + col]);
  *(u32x4*)(W2F + (size_t)e * 8) = *(u32x4*)v;
}

// ---- pre-kernel 2: bf16 copies of W1/b1, and b2sum[o] = sum_f b2[f][o] ----
__global__ void prep_small(const float* __restrict__ W1, const float* __restrict__ b1,
                           const float* __restrict__ b2, uint16_t* __restrict__ w1bf,
                           uint16_t* __restrict__ b1bf, float* __restrict__ b2sum) {
  const int t = blockIdx.x * 256 + threadIdx.x;  // 32*256 = 8192 = F*H
  w1bf[t] = rne_bf16(W1[t]);
  b1bf[t] = rne_bf16(b1[t]);
  if (t < ODIM) {
    float s = 0.f;
#pragma unroll
    for (int f = 0; f < FDIM; ++f) s += b2[(size_t)f * ODIM + t];
    b2sum[t] = s;
  }
}

// ---- main kernel: B direct global->VGPR (fragment-linear), A-only LDS ----
// BM=128 x BN=256, 512 thr = 8 waves: wave = (mh= wid>>2)*64 rows, (wc=wid&3)*64 cols.
// Grid 256 = 1 block/CU. elu recompute x2. LDS = 2 x 16KB A double-buffer only;
// one barrier per k-step; B(s+1) VGPR-prefetch issued right after barrier s.
__global__ __launch_bounds__(512, 2) void mlp_gemm(
    const float* __restrict__ x, const uint16_t* __restrict__ w1bf,
    const uint16_t* __restrict__ b1bf, const uint16_t* __restrict__ W2F,
    const float* __restrict__ b2sum, float* __restrict__ out) {
  __shared__ __align__(16) uint16_t As[2][BM * BK];  // 2 x 16 KB

  const int tid = threadIdx.x;
  const int bid = blockIdx.x;
  const int oh = bid & 1;            // o-half; bid&1 => uniform per XCD (round-robin)
  const int m0 = (bid >> 1) * BM;

  const int wid = tid >> 6;
  const int lane = tid & 63;
  const int mh = wid >> 2;           // M-half (0/1)
  const int wc = wid & 3;            // 64-col slice within the 256-col half
  const int q = lane >> 4;
  const int r = lane & 15;

  // A-gen roles: 4 threads per row, each thread 2 col-groups (16 elems)
  const int arow = tid >> 2;                         // 0..127
  const int g1 = (tid & 3) + 4 * (arow & 1);         // alternating halves ->
  const int g2 = g1 ^ 4;                             // conflict-free b128 writes

  // wave-uniform W2F base (elements): [oh][step][kc][wc][nt][lane] strides
  const uint16_t* wbase = W2F + (size_t)oh * 2097152 + (size_t)wc * 2048 + lane * 8;

  f32x4 acc[4][4];
#pragma unroll
  for (int i = 0; i < 4; ++i)
#pragma unroll
    for (int j = 0; j < 4; ++j) acc[i][j] = {0.f, 0.f, 0.f, 0.f};

  auto loadB = [&](int step, bf16x8 (&dst)[8]) {
    const uint16_t* p = wbase + (size_t)step * 16384;
#pragma unroll
    for (int kc = 0; kc < 2; ++kc)
#pragma unroll
      for (int nt = 0; nt < 4; ++nt)
        dst[kc * 4 + nt] = *(const bf16x8*)(p + kc * 8192 + nt * 512);
  };

  auto genA = [&](int s, int buf) {
    const int f = s >> 1;
    const int half = s & 1;
    const float xv = x[(size_t)(m0 + arow) * FDIM + f];
#pragma unroll
    for (int gi = 0; gi < 2; ++gi) {
      const int g = gi ? g2 : g1;
      const int hoff = half * 64 + g * 8;
      u32x4 w1d = *(const u32x4*)(w1bf + f * HDIM + hoff);
      u32x4 b1d = *(const u32x4*)(b1bf + f * HDIM + hoff);
      u32x4 ov;
#pragma unroll
      for (int p = 0; p < 4; ++p) {
        float wlo = __builtin_bit_cast(float, w1d[p] << 16);
        float whi = __builtin_bit_cast(float, w1d[p] & 0xffff0000u);
        float blo = __builtin_bit_cast(float, b1d[p] << 16);
        float bhi = __builtin_bit_cast(float, b1d[p] & 0xffff0000u);
        float plo = fmaf(xv, wlo, blo);
        float phi = fmaf(xv, whi, bhi);
        float elo = plo > 0.f ? plo : __expf(plo) - 1.f;
        float ehi = phi > 0.f ? phi : __expf(phi) - 1.f;
        ov[p] = __builtin_amdgcn_perm(__builtin_bit_cast(uint32_t, ehi),
                                      __builtin_bit_cast(uint32_t, elo),
                                      0x07060302u);
      }
      *(u32x4*)&As[buf][arow * BK + ((g ^ (arow & 7)) * 8)] = ov;
    }
  };

  auto domfma = [&](int buf, bf16x8 (&rb)[8]) {
#pragma unroll
    for (int kc = 0; kc < 2; ++kc) {
      bf16x8 af[4];
      const int cg = kc * 4 + q;
#pragma unroll
      for (int mt = 0; mt < 4; ++mt) {
        const int row = mh * 64 + mt * 16 + r;
        af[mt] = *(const bf16x8*)&As[buf][row * BK + ((cg ^ (row & 7)) * 8)];
      }
#pragma unroll
      for (int mt = 0; mt < 4; ++mt)
#pragma unroll
        for (int nt = 0; nt < 4; ++nt)
          acc[mt][nt] = __builtin_amdgcn_mfma_f32_16x16x32_bf16(
              af[mt], rb[kc * 4 + nt], acc[mt][nt], 0, 0, 0);
    }
  };

  bf16x8 rb0[8], rb1[8];
  loadB(0, rb0);
  genA(0, 0);

  for (int s = 0; s < NSTEPS; s += 2) {
    __syncthreads();  // As[0](step s) ready; rb0 drained; As[1] free
    loadB(s + 1, rb1);                   // in flight through this whole step
    if (wid < 4) { genA(s + 1, 1); domfma(0, rb0); }
    else         { domfma(0, rb0); genA(s + 1, 1); }

    __syncthreads();  // As[1](step s+1) ready; rb1 drained; As[0] free
    if (s + 2 < NSTEPS) {
      loadB(s + 2, rb0);
      if (wid < 4) { genA(s + 2, 0); domfma(1, rb1); }
      else         { domfma(1, rb1); genA(s + 2, 0); }
    } else {
      domfma(1, rb1);
    }
  }

  // ---- epilogue: + sum_f b2, * 1/sqrt(F) ----
  const int o0 = oh * 256 + wc * 64;
  float bsv[4];
#pragma unroll
  for (int nt = 0; nt < 4; ++nt) bsv[nt] = b2sum[o0 + nt * 16 + r];
#pragma unroll
  for (int mt = 0; mt < 4; ++mt)
#pragma unroll
    for (int nt = 0; nt < 4; ++nt)
#pragma unroll
      for (int v = 0; v < 4; ++v) {
        const int row = m0 + mh * 64 + mt * 16 + q * 4 + v;  // C/D: row=(lane>>4)*4+reg
        const int col = o0 + nt * 16 + r;                    //      col=lane&15
        out[(size_t)row * ODIM + col] = (acc[mt][nt][v] + bsv[nt]) * 0.125f;
      }
}

extern "C" void kernel_launch(void* const* d_in, const int* in_sizes, int n_in,
                              void* d_out, int out_size, void* d_ws, size_t ws_size,
                              hipStream_t stream) {
  const float* x  = (const float*)d_in[0];
  const float* W1 = (const float*)d_in[1];
  const float* b1 = (const float*)d_in[2];
  const float* W2 = (const float*)d_in[3];
  const float* b2 = (const float*)d_in[4];
  float* out = (float*)d_out;

  char* ws = (char*)d_ws;
  float*    b2sum = (float*)ws;                       // 2KB
  uint16_t* w1bf  = (uint16_t*)(ws + 4096);           // 16KB
  uint16_t* b1bf  = (uint16_t*)(ws + 4096 + 16384);   // 16KB
  uint16_t* W2F   = (uint16_t*)(ws + 65536);          // 8MB fragment-linear bf16

  prep_w2f<<<2048, 256, 0, stream>>>(W2, W2F);
  prep_small<<<32, 256, 0, stream>>>(W1, b1, b2, w1bf, b1bf, b2sum);
  mlp_gemm<<<(NROWS / BM) * (ODIM / BN), 512, 0, stream>>>(x, w1bf, b1bf, W2F,
                                                           b2sum, out);
}

// Round 5
// 288.097 us; speedup vs baseline: 1.0373x; 1.0138x over previous
//
#include <hip/hip_runtime.h>
#include <cstdint>

#define NROWS 16384
#define FDIM 64
#define HDIM 128
#define ODIM 512
#define KDIM 8192    // FDIM * HDIM
#define NSTEPS 64    // k-steps per block (split-K/2: 64 * BK = 4096)

#define BM 128
#define BN 256
#define BK 64

typedef short bf16x8 __attribute__((ext_vector_type(8)));
typedef float f32x4 __attribute__((ext_vector_type(4)));
typedef uint32_t u32x4 __attribute__((ext_vector_type(4)));

__device__ __forceinline__ uint16_t rne_bf16(float f) {
  uint32_t u = __builtin_bit_cast(uint32_t, f);
  u += 0x7fffu + ((u >> 16) & 1u);
  return (uint16_t)(u >> 16);
}

// ---- pre-kernel 1: W2 [K=8192][O=512] f32 -> W2T [O][K] bf16 (LDS tile transpose) ----
__global__ void prep_w2t(const float* __restrict__ W2, uint16_t* __restrict__ W2T) {
  __shared__ float tile[64][65];
  const int k0 = blockIdx.x * 64;
  const int o0 = blockIdx.y * 64;
  const int tx = threadIdx.x;  // 0..63
  const int ty = threadIdx.y;  // 0..7
#pragma unroll
  for (int j = 0; j < 8; ++j)
    tile[ty + 8 * j][tx] = W2[(size_t)(k0 + ty + 8 * j) * ODIM + o0 + tx];
  __syncthreads();
#pragma unroll
  for (int j = 0; j < 8; ++j)
    W2T[(size_t)(o0 + ty + 8 * j) * KDIM + k0 + tx] = rne_bf16(tile[tx][ty + 8 * j]);
}

// ---- pre-kernel 2: bf16 copies of W1/b1, and b2sum[o] = sum_f b2[f][o] ----
__global__ void prep_small(const float* __restrict__ W1, const float* __restrict__ b1,
                           const float* __restrict__ b2, uint16_t* __restrict__ w1bf,
                           uint16_t* __restrict__ b1bf, float* __restrict__ b2sum) {
  const int t = blockIdx.x * 256 + threadIdx.x;  // 32*256 = 8192 = F*H
  w1bf[t] = rne_bf16(W1[t]);
  b1bf[t] = rne_bf16(b1[t]);
  if (t < ODIM) {
    float s = 0.f;
#pragma unroll
    for (int f = 0; f < FDIM; ++f) s += b2[(size_t)f * ODIM + t];
    b2sum[t] = s;
  }
}

// ---- main kernel: split-K x2, BM=128 x BN=256, 256 thr (4 waves of 64x128) ----
// bid bits: oh=bid&1, kh=(bid>>1)&1, m=(bid>>2). With bid%8 -> XCD round-robin,
// each XCD sees a FIXED (oh,kh) => its W2T working set is 4096x256 bf16 = 2MB,
// L2-resident (the 9-10 TB/s L3 ceiling observed R1-R4 becomes a ~30 TB/s L2 path).
// Grid 512 = 2 blocks/CU for cross-block latency hiding. elu recompute x2 (oh only).
// Split-K reduction: f32 atomicAdd into memset-zeroed out; kh=0 adds the bias.
__global__ __launch_bounds__(256, 2) void mlp_gemm(
    const float* __restrict__ x, const uint16_t* __restrict__ w1bf,
    const uint16_t* __restrict__ b1bf, const uint16_t* __restrict__ W2T,
    const float* __restrict__ b2sum, float* __restrict__ out) {
  __shared__ __align__(16) uint16_t As[BM * BK];  // 16 KB
  __shared__ __align__(16) uint16_t Bs[BN * BK];  // 32 KB

  const int tid = threadIdx.x;
  const int bid = blockIdx.x;
  const int oh = bid & 1;
  const int kh = (bid >> 1) & 1;
  const int m0 = (bid >> 2) * BM;
  const int o0 = oh * BN;

  const int wid = tid >> 6;
  const int lane = tid & 63;
  const int mh = wid >> 1;   // wave m-half (64 rows)
  const int nh = wid & 1;    // wave n-half (128 cols)
  const int q = lane >> 4;
  const int r = lane & 15;

  // A-gen roles: 2 threads per row; each thread 4 col-groups (32 elems)
  const int arow = tid >> 1;            // 0..127
  const int gbase = (tid & 1) * 4;      // col-groups gbase..gbase+3
  // B-staging roles (global_load_lds: LDS = wave-uniform base + lane*16;
  // swizzle the GLOBAL col-group so fragment reads stay conflict-free)
  const int brow = lane >> 3;           // 0..7 within an 8-row chunk
  const int bcg = (lane & 7) ^ brow;    // swizzled col group

  f32x4 acc[4][8];
#pragma unroll
  for (int i = 0; i < 4; ++i)
#pragma unroll
    for (int j = 0; j < 8; ++j) acc[i][j] = {0.f, 0.f, 0.f, 0.f};

  for (int s = 0; s < NSTEPS; ++s) {
    const int kstep = kh * 64 + s;      // global k-step (k0 = kstep*64)
    __syncthreads();                    // previous tile fully consumed

    // -- stage B: 8 async 1KB chunks per wave (32 chunks of 8 o-rows) --
#pragma unroll
    for (int j = 0; j < 8; ++j) {
      const int chunk = wid * 8 + j;    // 0..31
      const uint16_t* gp =
          W2T + (size_t)(o0 + chunk * 8 + brow) * KDIM + kstep * BK + bcg * 8;
      uint16_t* lp = &Bs[chunk * 512];  // wave-uniform base
      __builtin_amdgcn_global_load_lds(
          (const __attribute__((address_space(1))) uint32_t*)gp,
          (__attribute__((address_space(3))) uint32_t*)lp, 16, 0, 0);
    }

    // -- stage A: elu(x*w1+b1) -> bf16, 32 elems/thread --
    {
      const int f = kh * 32 + (s >> 1);
      const int half = s & 1;
      const float xv = x[(size_t)(m0 + arow) * FDIM + f];
#pragma unroll
      for (int gi = 0; gi < 4; ++gi) {
        const int g = gbase + gi;
        const int hoff = half * 64 + g * 8;
        u32x4 w1d = *(const u32x4*)(w1bf + f * HDIM + hoff);
        u32x4 b1d = *(const u32x4*)(b1bf + f * HDIM + hoff);
        u32x4 ov;
#pragma unroll
        for (int p = 0; p < 4; ++p) {
          float wlo = __builtin_bit_cast(float, w1d[p] << 16);
          float whi = __builtin_bit_cast(float, w1d[p] & 0xffff0000u);
          float blo = __builtin_bit_cast(float, b1d[p] << 16);
          float bhi = __builtin_bit_cast(float, b1d[p] & 0xffff0000u);
          float plo = fmaf(xv, wlo, blo);
          float phi = fmaf(xv, whi, bhi);
          float elo = plo > 0.f ? plo : __expf(plo) - 1.f;
          float ehi = phi > 0.f ? phi : __expf(phi) - 1.f;
          ov[p] = __builtin_amdgcn_perm(__builtin_bit_cast(uint32_t, ehi),
                                        __builtin_bit_cast(uint32_t, elo),
                                        0x07060302u);
        }
        *(u32x4*)&As[arow * BK + ((g ^ (arow & 7)) * 8)] = ov;
      }
    }
    __syncthreads();  // drains vmcnt (global_load_lds) + lgkm

    // -- compute: 2 k-chunks x (4 A-frags x 8 B-frags) = 64 mfma/step --
#pragma unroll
    for (int kc = 0; kc < 2; ++kc) {
      const int cg = kc * 4 + q;
      bf16x8 af[4];
#pragma unroll
      for (int mt = 0; mt < 4; ++mt) {
        const int row = mh * 64 + mt * 16 + r;
        af[mt] = *(const bf16x8*)&As[row * BK + ((cg ^ (row & 7)) * 8)];
      }
#pragma unroll
      for (int nt = 0; nt < 8; ++nt) {
        const int row = nh * 128 + nt * 16 + r;
        bf16x8 bf = *(const bf16x8*)&Bs[row * BK + ((cg ^ (row & 7)) * 8)];
#pragma unroll
        for (int mt = 0; mt < 4; ++mt)
          acc[mt][nt] = __builtin_amdgcn_mfma_f32_16x16x32_bf16(
              af[mt], bf, acc[mt][nt], 0, 0, 0);
      }
    }
  }

  // ---- epilogue: atomic accumulate (out pre-zeroed); kh=0 adds summed bias ----
#pragma unroll
  for (int nt = 0; nt < 8; ++nt) {
    const int col = o0 + nh * 128 + nt * 16 + r;
    const float bias = (kh == 0) ? b2sum[col] * 0.125f : 0.f;
#pragma unroll
    for (int mt = 0; mt < 4; ++mt)
#pragma unroll
      for (int v = 0; v < 4; ++v) {
        const int row = m0 + mh * 64 + mt * 16 + q * 4 + v;  // C/D: row=(lane>>4)*4+reg
        unsafeAtomicAdd(&out[(size_t)row * ODIM + col],
                        acc[mt][nt][v] * 0.125f + bias);
      }
  }
}

extern "C" void kernel_launch(void* const* d_in, const int* in_sizes, int n_in,
                              void* d_out, int out_size, void* d_ws, size_t ws_size,
                              hipStream_t stream) {
  const float* x  = (const float*)d_in[0];
  const float* W1 = (const float*)d_in[1];
  const float* b1 = (const float*)d_in[2];
  const float* W2 = (const float*)d_in[3];
  const float* b2 = (const float*)d_in[4];
  float* out = (float*)d_out;

  char* ws = (char*)d_ws;
  float*    b2sum = (float*)ws;                       // 2KB
  uint16_t* w1bf  = (uint16_t*)(ws + 4096);           // 16KB
  uint16_t* b1bf  = (uint16_t*)(ws + 4096 + 16384);   // 16KB
  uint16_t* W2T   = (uint16_t*)(ws + 65536);          // 8MB [O][K] bf16

  hipMemsetAsync(out, 0, (size_t)NROWS * ODIM * sizeof(float), stream);
  prep_w2t<<<dim3(KDIM / 64, ODIM / 64), dim3(64, 8), 0, stream>>>(W2, W2T);
  prep_small<<<32, 256, 0, stream>>>(W1, b1, b2, w1bf, b1bf, b2sum);
  // grid 512 = 128 m-blocks x 2 o-halves x 2 k-halves = 2 blocks/CU
  mlp_gemm<<<512, 256, 0, stream>>>(x, w1bf, b1bf, W2T, b2sum, out);
}